// Round 1
// baseline (476.742 us; speedup 1.0000x reference)
//
#include <hip/hip_runtime.h>
#include <math.h>

typedef float    float4_t __attribute__((ext_vector_type(4)));
typedef _Float16 half8    __attribute__((ext_vector_type(8)));
typedef _Float16 half4_t  __attribute__((ext_vector_type(4)));

// ---------------- Kernel P: fused h-GEMM + s1/s2 + hT(fp16) ------------------
__global__ __launch_bounds__(256) void k_prep(const float* __restrict__ inp,
                                              const float* __restrict__ W,
                                              const float* __restrict__ a,
                                              float* __restrict__ s1,
                                              float* __restrict__ s2,
                                              _Float16* __restrict__ hT) {
    __shared__ float sA[32 * 68];
    __shared__ float sW[64 * 128];
    const int t   = threadIdx.x;
    const int gr0 = blockIdx.x * 32;          // global row base (0..16383)
    const int b   = gr0 >> 12;                // batch
    const int f0  = (t & 15) * 8;
    const int r0  = (t >> 4) * 2;
    float4_t acc0[2] = {}; float4_t acc1[2] = {};
    for (int kc = 0; kc < 4; ++kc) {
        __syncthreads();
        #pragma unroll
        for (int it = 0; it < 2; ++it) {      // stage inp 32x64
            int fi = it * 256 + t; int r = fi >> 4; int c = (fi & 15) * 4;
            *(float4_t*)&sA[r * 68 + c] =
                *(const float4_t*)&inp[(size_t)(gr0 + r) * 256 + kc * 64 + c];
        }
        #pragma unroll
        for (int it = 0; it < 8; ++it) {      // stage W 64x128
            int fi = it * 256 + t; int k = fi >> 5; int c = (fi & 31) * 4;
            *(float4_t*)&sW[k * 128 + c] =
                *(const float4_t*)&W[(size_t)(kc * 64 + k) * 128 + c];
        }
        __syncthreads();
        for (int k = 0; k < 64; ++k) {
            float4_t w0 = *(const float4_t*)&sW[k * 128 + f0];
            float4_t w1 = *(const float4_t*)&sW[k * 128 + f0 + 4];
            #pragma unroll
            for (int r = 0; r < 2; ++r) {
                float av = sA[(r0 + r) * 68 + k];
                acc0[r] += av * w0; acc1[r] += av * w1;
            }
        }
    }
    float4_t a1lo = *(const float4_t*)&a[f0];
    float4_t a1hi = *(const float4_t*)&a[f0 + 4];
    float4_t a2lo = *(const float4_t*)&a[128 + f0];
    float4_t a2hi = *(const float4_t*)&a[128 + f0 + 4];
    #pragma unroll
    for (int r = 0; r < 2; ++r) {
        const int row  = gr0 + r0 + r;
        const int rloc = row & 4095;
        #pragma unroll
        for (int c = 0; c < 4; ++c) {
            hT[(size_t)b * (128 * 4096) + (size_t)(f0 + c) * 4096 + rloc]     = (_Float16)acc0[r][c];
            hT[(size_t)b * (128 * 4096) + (size_t)(f0 + 4 + c) * 4096 + rloc] = (_Float16)acc1[r][c];
        }
        float p1 = acc0[r][0]*a1lo[0] + acc0[r][1]*a1lo[1] + acc0[r][2]*a1lo[2] + acc0[r][3]*a1lo[3]
                 + acc1[r][0]*a1hi[0] + acc1[r][1]*a1hi[1] + acc1[r][2]*a1hi[2] + acc1[r][3]*a1hi[3];
        float p2 = acc0[r][0]*a2lo[0] + acc0[r][1]*a2lo[1] + acc0[r][2]*a2lo[2] + acc0[r][3]*a2lo[3]
                 + acc1[r][0]*a2hi[0] + acc1[r][1]*a2hi[1] + acc1[r][2]*a2hi[2] + acc1[r][3]*a2hi[3];
        #pragma unroll
        for (int o = 1; o < 16; o <<= 1) { p1 += __shfl_xor(p1, o); p2 += __shfl_xor(p2, o); }
        if ((t & 15) == 0) { s1[row] = p1; s2[row] = p2; }
    }
}

// ---------------- Kernel M: per-batch s2 max ---------------------------------
__global__ __launch_bounds__(256) void k_s2max(const float* __restrict__ s2,
                                               float* __restrict__ s2max) {
    const int b = blockIdx.x, t = threadIdx.x;
    float m = -INFINITY;
    for (int i = t; i < 4096; i += 256) m = fmaxf(m, s2[b * 4096 + i]);
    #pragma unroll
    for (int o = 1; o < 64; o <<= 1) m = fmaxf(m, __shfl_xor(m, o));
    __shared__ float sm[4];
    if ((t & 63) == 0) sm[t >> 6] = m;
    __syncthreads();
    if (t == 0) s2max[b] = fmaxf(fmaxf(sm[0], sm[1]), fmaxf(sm[2], sm[3]));
}

// ---------------- Kernel F: fixed-max attention + P@H ------------------------
// Grid 1024 x 256 (4 j-splits x 64 row-blocks x 4 batches). Wave = 16 rows.
// BARRIER-FREE: pbuf is wave-private (lgkmcnt(0) only); B-fragments are read
// as half8 DIRECTLY from global hT (4 MB, L2/L3-resident, contiguous in the
// exact MFMA k-slice order), so no hT LDS staging and no __syncthreads at all
// -> the 16 waves/CU drift freely. adj + s2 are register-prefetched one
// j-tile ahead (reloaded into the same regs right after the p-compute consumes
// them), so HBM latency hides under the pbuf/afrag/MFMA phase. B-frag pairs
// ping-pong inside the fully-unrolled nt loop so one pair is always in flight.
__global__ __launch_bounds__(256, 4) void k_flash(const float* __restrict__ adj,
                                                  const _Float16* __restrict__ hT,
                                                  const float* __restrict__ s1,
                                                  const float* __restrict__ s2,
                                                  const float* __restrict__ s2max,
                                                  float* __restrict__ part_acc,
                                                  float* __restrict__ part_l) {
    __shared__ _Float16 pbuf[4][16 * 64];     // 8 KB, wave-private p tiles

    const int t    = threadIdx.x;
    const int bid  = blockIdx.x;
    const int sp   = bid & 3;                 // j-split
    const int rb   = (bid >> 2) & 63;         // 64-row block within batch
    const int b    = bid >> 8;                // batch
    const int w    = t >> 6, lane = t & 63;
    const int quad = lane >> 4, ln15 = lane & 15;
    const int g    = quad;                    // row-group for p-compute
    const int cl   = ln15;                    // col-lane for p-compute
    const int rowb = rb * 64 + w * 16;        // wave's 16-row base
    const float*    adj_w = adj + (size_t)b * 4096 * 4096 + (size_t)rowb * 4096;
    const _Float16* hT_b  = hT + (size_t)b * 128 * 4096;
    const float*    s2_b  = s2 + b * 4096;
    const float     s2m   = s2max[b];
    const int jwbase = sp * 1024;

    float s1r[4], mh[4];
    #pragma unroll
    for (int L = 0; L < 4; ++L) {
        s1r[L] = s1[b * 4096 + rowb + L * 4 + g];
        mh[L]  = fmaxf(0.f, s1r[L] + s2m);
    }

    // per-lane hT base for direct B-fragment loads:
    // BLOAD(nt,kc) = hT_b[(nt*16+ln15)*4096 + j0 + (kc*4+quad)*8]
    const _Float16* hT_lane = hT_b + (size_t)ln15 * 4096 + (quad << 3);

    float4_t acc[8] = {};
    float4_t psacc = {0.f, 0.f, 0.f, 0.f};

    // ---- prologue: adj/s2 for jt=0 ----
    float4_t av[4];
    float4_t s2v;
    #pragma unroll
    for (int L = 0; L < 4; ++L)
        av[L] = *(const float4_t*)&adj_w[(size_t)(L * 4 + g) * 4096 + jwbase + cl * 4];
    s2v = *(const float4_t*)&s2_b[jwbase + cl * 4];

    for (int jt = 0; jt < 16; ++jt) {
        const int j0 = jwbase + jt * 64;
        // ---- p = exp(adj*leaky(s1+s2) - mhat), write to wave-private pbuf ----
        #pragma unroll
        for (int L = 0; L < 4; ++L) {
            half4_t qv;
            #pragma unroll
            for (int c = 0; c < 4; ++c) {
                float x = s1r[L] + s2v[c];
                float e = x > 0.f ? x : 0.2f * x;
                float p = av[L][c] > 0.f ? __expf(fmaf(av[L][c], e, -mh[L])) : 0.f;
                _Float16 q = (_Float16)p;
                qv[c] = q;
                psacc[L] += (float)q;
            }
            const int r     = L * 4 + g;
            const int c0    = cl * 4;
            const int chunk = (c0 >> 3) ^ (r & 7);
            *(half4_t*)&pbuf[w][r * 64 + chunk * 8 + (c0 & 7)] = qv;
        }
        // ---- register-prefetch adj/s2 for jt+1 (av fully consumed above) ----
        if (jt < 15) {
            #pragma unroll
            for (int L = 0; L < 4; ++L)
                av[L] = *(const float4_t*)&adj_w[(size_t)(L * 4 + g) * 4096 + j0 + 64 + cl * 4];
            s2v = *(const float4_t*)&s2_b[j0 + 64 + cl * 4];
        }
        // ---- first B-frag pair in flight before the LDS wait ----
        half8 bf[2][2];
        bf[0][0] = *(const half8*)&hT_lane[j0];
        bf[0][1] = *(const half8*)&hT_lane[j0 + 32];
        // wave-private pbuf: writes visible to this wave's reads after lgkmcnt(0)
        asm volatile("s_waitcnt lgkmcnt(0)" ::: "memory");
        // ---- A-frags from pbuf ----
        half8 afrag[2];
        #pragma unroll
        for (int kc = 0; kc < 2; ++kc) {
            const int chunk = ((kc << 2) + quad) ^ (ln15 & 7);
            afrag[kc] = *(const half8*)&pbuf[w][ln15 * 64 + chunk * 8];
        }
        // ---- MFMA with ping-ponged direct-global B-frags ----
        #pragma unroll
        for (int nt = 0; nt < 8; ++nt) {
            const int cb = nt & 1;
            if (nt < 7) {
                bf[cb ^ 1][0] = *(const half8*)&hT_lane[(size_t)(nt + 1) * 16 * 4096 + j0];
                bf[cb ^ 1][1] = *(const half8*)&hT_lane[(size_t)(nt + 1) * 16 * 4096 + j0 + 32];
            }
            acc[nt] = __builtin_amdgcn_mfma_f32_16x16x32_f16(afrag[0], bf[cb][0], acc[nt], 0, 0, 0);
            acc[nt] = __builtin_amdgcn_mfma_f32_16x16x32_f16(afrag[1], bf[cb][1], acc[nt], 0, 0, 0);
        }
    }
    // ---- epilogue: reduce l within each 16-lane group, write partials ----
    #pragma unroll
    for (int o = 1; o < 16; o <<= 1) {
        #pragma unroll
        for (int L = 0; L < 4; ++L) psacc[L] += __shfl_xor(psacc[L], o);
    }
    const size_t growb = (size_t)b * 4096 + rowb;
    if (cl == 0) {
        #pragma unroll
        for (int L = 0; L < 4; ++L)
            part_l[(size_t)sp * 16384 + growb + L * 4 + g] = psacc[L];
    }
    float* pacc = part_acc + (size_t)sp * 16384 * 128;
    #pragma unroll
    for (int nt = 0; nt < 8; ++nt) {
        #pragma unroll
        for (int reg = 0; reg < 4; ++reg) {
            pacc[(growb + quad * 4 + reg) * 128 + nt * 16 + ln15] = acc[nt][reg];
        }
    }
}

// ---------------- Kernel E: sum 4 j-split partials, normalize, elu -----------
__global__ __launch_bounds__(256) void k_combine(const float* __restrict__ part_acc,
                                                 const float* __restrict__ part_l,
                                                 float* __restrict__ out) {
    const int idx = blockIdx.x * 256 + threadIdx.x;   // 0..524287
    const int e0  = idx * 4;
    const int gr  = e0 >> 7;
    float l = part_l[gr] + part_l[16384 + gr] + part_l[32768 + gr] + part_l[49152 + gr];
    float4_t a0 = *(const float4_t*)&part_acc[e0];
    float4_t a1 = *(const float4_t*)&part_acc[2097152 + e0];
    float4_t a2 = *(const float4_t*)&part_acc[4194304 + e0];
    float4_t a3 = *(const float4_t*)&part_acc[6291456 + e0];
    float4_t s  = (a0 + a1) + (a2 + a3);
    float rl = 1.f / l;
    float4_t o;
    #pragma unroll
    for (int c = 0; c < 4; ++c) {
        float v = s[c] * rl;
        o[c] = v > 0.f ? v : expm1f(v);
    }
    *(float4_t*)&((float*)out)[e0] = o;
}

extern "C" void kernel_launch(void* const* d_in, const int* in_sizes, int n_in,
                              void* d_out, int out_size, void* d_ws, size_t ws_size,
                              hipStream_t stream) {
    const float* inp = (const float*)d_in[0];   // (4,4096,256)
    const float* adj = (const float*)d_in[1];   // (4,4096,4096)
    const float* W   = (const float*)d_in[2];   // (256,128)
    const float* a   = (const float*)d_in[3];   // (256,1)
    float* out = (float*)d_out;                 // (4,4096,128)

    char* wsb = (char*)d_ws;
    _Float16* hT       = (_Float16*)(wsb);                // 4 MB
    float*    s1       = (float*)(wsb + 4194304);         // 64 KB
    float*    s2       = (float*)(wsb + 4259840);         // 64 KB
    float*    s2max    = (float*)(wsb + 4325376);         // 256 B
    float*    part_l   = (float*)(wsb + 4325632);         // 256 KB
    float*    part_acc = (float*)(wsb + 4587776);         // 32 MB (total ~36.4 MB)

    hipLaunchKernelGGL(k_prep,    dim3(512),  dim3(256), 0, stream, inp, W, a, s1, s2, hT);
    hipLaunchKernelGGL(k_s2max,   dim3(4),    dim3(256), 0, stream, s2, s2max);
    hipLaunchKernelGGL(k_flash,   dim3(1024), dim3(256), 0, stream, adj, hT, s1, s2, s2max,
                       part_acc, part_l);
    hipLaunchKernelGGL(k_combine, dim3(2048), dim3(256), 0, stream, part_acc, part_l, out);
}